// Round 5
// baseline (172.653 us; speedup 1.0000x reference)
//
#include <hip/hip_runtime.h>
#include <hip/hip_bf16.h>

// GAT layer, N=8192 Fin=256 Fout=64.
// k1: Wh = h@W, s1/s2 = Wh@a halves (s2 pre-scaled by log2e), whT hi/lo bf16.
// k2 v4: barrier-free fused attention (as v3) +
//   - COMPILER-FENCED 4-slot prefetch rotation: asm volatile memory clobber
//     after each load group prevents the compiler sinking loads (R4: VGPR=84
//     proved the rotation was collapsed; latency fully exposed).
//   - exp2-direct path: s2 pre-scaled by log2e, __builtin_amdgcn_exp2f.

typedef __attribute__((ext_vector_type(8))) short bf16x8;
typedef __attribute__((ext_vector_type(16))) float f32x16;

#define QB 32
#define KS 16
#define NS 128   // ksteps per wave = 2048/16
#define LOG2E 1.4426950408889634f

#define FENCE asm volatile("" ::: "memory")

__device__ __forceinline__ uint pk2(float a, float b, float& ra, float& rb) {
    __hip_bfloat162 h = __float22bfloat162_rn(make_float2(a, b));
    float2 f = __bfloat1622float2(h);
    ra = f.x; rb = f.y;
    union { __hip_bfloat162 b; uint u; } c; c.b = h; return c.u;
}
__device__ __forceinline__ uint pk2o(float a, float b) {
    __hip_bfloat162 h = __float22bfloat162_rn(make_float2(a, b));
    union { __hip_bfloat162 b; uint u; } c; c.b = h; return c.u;
}
__device__ __forceinline__ ushort f2bf(float x) {
    union { __hip_bfloat16 b; ushort u; } c;
    c.b = __float2bfloat16(x);
    return c.u;
}
__device__ __forceinline__ float bf2f(ushort u) {
    union { ushort u; __hip_bfloat16 b; } c;
    c.u = u;
    return __bfloat162float(c.b);
}

// ---------------- kernel 1: Wh, s1, s2*log2e, WhT hi/lo ----------------
__global__ __launch_bounds__(256) void k1_wh(
    const float* __restrict__ h, const float* __restrict__ W,
    const float* __restrict__ a,
    float* __restrict__ s1, float* __restrict__ s2,
    ushort* __restrict__ whT_hi, ushort* __restrict__ whT_lo)
{
    const int l = threadIdx.x & 63;      // lane = output feature
    const int w = threadIdx.x >> 6;
    const int row0 = blockIdx.x * 16 + w * 4;

    float acc[4] = {0.f, 0.f, 0.f, 0.f};
    for (int k = 0; k < 256; k += 4) {
        float w0 = W[(k + 0) * 64 + l];
        float w1 = W[(k + 1) * 64 + l];
        float w2 = W[(k + 2) * 64 + l];
        float w3 = W[(k + 3) * 64 + l];
#pragma unroll
        for (int r = 0; r < 4; ++r) {
            const float4 hv = *reinterpret_cast<const float4*>(&h[(row0 + r) * 256 + k]);
            acc[r] = fmaf(hv.x, w0, acc[r]);
            acc[r] = fmaf(hv.y, w1, acc[r]);
            acc[r] = fmaf(hv.z, w2, acc[r]);
            acc[r] = fmaf(hv.w, w3, acc[r]);
        }
    }
    const float a1 = a[l];
    const float a2 = a[64 + l];
#pragma unroll
    for (int r = 0; r < 4; ++r) {
        const int row = row0 + r;
        float x1 = acc[r] * a1;
        float x2 = acc[r] * a2;
#pragma unroll
        for (int m = 32; m >= 1; m >>= 1) {
            x1 += __shfl_xor(x1, m);
            x2 += __shfl_xor(x2, m);
        }
        if (l == 0) { s1[row] = x1; s2[row] = x2 * LOG2E; }
        const ushort hi = f2bf(acc[r]);
        const ushort lo = f2bf(acc[r] - bf2f(hi));
        whT_hi[l * 8192 + row] = hi;
        whT_lo[l * 8192 + row] = lo;
    }
}

// ---------------- kernel 2: barrier-free fused attention ----------------

#define LD(S, T) do { \
    av##S##a = *reinterpret_cast<const int4*>(aptr + (size_t)(T) * KS); \
    av##S##b = *reinterpret_cast<const int4*>(aptr + (size_t)(T) * KS + 4); \
    sv##S##a = *reinterpret_cast<const float4*>(sptr + (size_t)(T) * KS); \
    sv##S##b = *reinterpret_cast<const float4*>(sptr + (size_t)(T) * KS + 4); \
  } while (0)

#define WH(S, T) do { \
    wh##S##h = *reinterpret_cast<const bf16x8*>(whp + (size_t)(T) * KS); \
    wh##S##l = *reinterpret_cast<const bf16x8*>(wlp + (size_t)(T) * KS); \
  } while (0)

// t1,t2 already in log2 domain (s2 pre-scaled by log2e in k1)
#define PEXP(dst, a_, s_) { \
    const float t1_ = A + (s_); \
    const float t2_ = fmaf(0.2f, (s_), A5); \
    dst = __builtin_amdgcn_exp2f(fmaxf(t1_, t2_)); \
    if ((a_) <= 0) dst = 0.0f; \
    rs += dst; }

#define STEP(S) do { \
    float p0,p1,p2,p3,p4,p5,p6,p7, r0,r1,r2,r3,r4,r5,r6,r7; \
    PEXP(p0, (av##S##a).x, (sv##S##a).x) \
    PEXP(p1, (av##S##a).y, (sv##S##a).y) \
    PEXP(p2, (av##S##a).z, (sv##S##a).z) \
    PEXP(p3, (av##S##a).w, (sv##S##a).w) \
    PEXP(p4, (av##S##b).x, (sv##S##b).x) \
    PEXP(p5, (av##S##b).y, (sv##S##b).y) \
    PEXP(p6, (av##S##b).z, (sv##S##b).z) \
    PEXP(p7, (av##S##b).w, (sv##S##b).w) \
    union PKU { bf16x8 v; uint u[4]; } bh_, bl_; \
    bh_.u[0] = pk2(p0, p1, r0, r1); \
    bh_.u[1] = pk2(p2, p3, r2, r3); \
    bh_.u[2] = pk2(p4, p5, r4, r5); \
    bh_.u[3] = pk2(p6, p7, r6, r7); \
    bl_.u[0] = pk2o(p0 - r0, p1 - r1); \
    bl_.u[1] = pk2o(p2 - r2, p3 - r3); \
    bl_.u[2] = pk2o(p4 - r4, p5 - r5); \
    bl_.u[3] = pk2o(p6 - r6, p7 - r7); \
    acc = __builtin_amdgcn_mfma_f32_32x32x16_bf16(wh##S##h, bh_.v, acc, 0, 0, 0); \
    acc = __builtin_amdgcn_mfma_f32_32x32x16_bf16(wh##S##h, bl_.v, acc, 0, 0, 0); \
    acc = __builtin_amdgcn_mfma_f32_32x32x16_bf16(wh##S##l, bh_.v, acc, 0, 0, 0); \
  } while (0)

__global__ __launch_bounds__(512, 2) void k2_attn(
    const int* __restrict__ adj,
    const float* __restrict__ s1g, const float* __restrict__ s2g,
    const ushort* __restrict__ whT_hi, const ushort* __restrict__ whT_lo,
    float* __restrict__ out)
{
    __shared__ __align__(16) float slds[2][3][64][16];   // ks 1..3 partial accs
    __shared__ float dlds[4][32];                        // per-quarter denoms

    const int t   = threadIdx.x;
    const int l   = t & 63;
    const int wv  = t >> 6;
    const int ft  = wv >> 2;          // 0..1 : feature half (32 feats)
    const int ks  = wv & 3;           // 0..3 : j quarter (2048 cols)
    const int row = l & 31;           // node-row within tile = B-frag col
    const int kh  = l >> 5;           // k-half within fragment
    const int i0  = blockIdx.x * QB;
    const int ftbase = ft * 32;
    const int jbase  = ks * 2048;

    const float s1v = s1g[i0 + row];
    const float mq  = s1v + 16.0f;
    const float m   = fmaxf(mq, 0.2f * mq);       // fixed row-max upper bound
    const float A   = (s1v - m) * LOG2E;          // log2-domain constants
    const float A5  = fmaf(0.2f, s1v, -m) * LOG2E;

    const int*    aptr = adj    + (size_t)(i0 + row) * 8192 + jbase + kh * 8;
    const float*  sptr = s2g    + jbase + kh * 8;
    const ushort* whp  = whT_hi + (size_t)(ftbase + row) * 8192 + jbase + kh * 8;
    const ushort* wlp  = whT_lo + (size_t)(ftbase + row) * 8192 + jbase + kh * 8;

    f32x16 acc = {0.f,0.f,0.f,0.f,0.f,0.f,0.f,0.f,0.f,0.f,0.f,0.f,0.f,0.f,0.f,0.f};
    float rs = 0.f;

    int4   av0a, av0b, av1a, av1b, av2a, av2b, av3a, av3b;
    float4 sv0a, sv0b, sv1a, sv1b, sv2a, sv2b, sv3a, sv3b;
    bf16x8 wh0h, wh0l, wh1h, wh1l, wh2h, wh2l, wh3h, wh3l;

    LD(0, 0); WH(0, 0); FENCE;
    LD(1, 1); WH(1, 1); FENCE;
    LD(2, 2); WH(2, 2); FENCE;
    LD(3, 3); WH(3, 3); FENCE;

    for (int T = 0; T + 4 < NS; T += 4) {   // T = 0,4,...,120
        STEP(0); LD(0, T + 4); WH(0, T + 4); FENCE;
        STEP(1); LD(1, T + 5); WH(1, T + 5); FENCE;
        STEP(2); LD(2, T + 6); WH(2, T + 6); FENCE;
        STEP(3); LD(3, T + 7); WH(3, T + 7); FENCE;
    }
    STEP(0); STEP(1); STEP(2); STEP(3);     // T = 124..127

    // ---- epilogue: combine 4 ks-partials ----
    rs += __shfl_xor(rs, 32);               // lanes l, l+32 hold same row
    if (ft == 0 && kh == 0) dlds[ks][row] = rs;
    if (ks != 0) {
        float4* dst = reinterpret_cast<float4*>(&slds[ft][ks - 1][l][0]);
        dst[0] = make_float4(acc[0],  acc[1],  acc[2],  acc[3]);
        dst[1] = make_float4(acc[4],  acc[5],  acc[6],  acc[7]);
        dst[2] = make_float4(acc[8],  acc[9],  acc[10], acc[11]);
        dst[3] = make_float4(acc[12], acc[13], acc[14], acc[15]);
    }
    __syncthreads();
    if (ks == 0) {
#pragma unroll
        for (int s = 0; s < 3; ++s) {
            const float4* src = reinterpret_cast<const float4*>(&slds[ft][s][l][0]);
            const float4 v0 = src[0], v1 = src[1], v2 = src[2], v3 = src[3];
            acc[0]  += v0.x; acc[1]  += v0.y; acc[2]  += v0.z; acc[3]  += v0.w;
            acc[4]  += v1.x; acc[5]  += v1.y; acc[6]  += v1.z; acc[7]  += v1.w;
            acc[8]  += v2.x; acc[9]  += v2.y; acc[10] += v2.z; acc[11] += v2.w;
            acc[12] += v3.x; acc[13] += v3.y; acc[14] += v3.z; acc[15] += v3.w;
        }
        const float den = dlds[0][row] + dlds[1][row] + dlds[2][row] + dlds[3][row];
        const float inv = 1.0f / den;
        const int orow = i0 + row;
        // D layout (32x32): col=l&31 -> node row; feat = (reg&3)+8*(reg>>2)+4*kh
#pragma unroll
        for (int g = 0; g < 4; ++g) {
            float4 o; float x;
            x = acc[g * 4 + 0] * inv; o.x = (x > 0.f) ? x : expm1f(x);
            x = acc[g * 4 + 1] * inv; o.y = (x > 0.f) ? x : expm1f(x);
            x = acc[g * 4 + 2] * inv; o.z = (x > 0.f) ? x : expm1f(x);
            x = acc[g * 4 + 3] * inv; o.w = (x > 0.f) ? x : expm1f(x);
            *reinterpret_cast<float4*>(&out[orow * 64 + ftbase + 8 * g + 4 * kh]) = o;
        }
    }
}

extern "C" void kernel_launch(void* const* d_in, const int* in_sizes, int n_in,
                              void* d_out, int out_size, void* d_ws, size_t ws_size,
                              hipStream_t stream) {
    const float* h   = (const float*)d_in[0];
    const int*   adj = (const int*)d_in[1];
    const float* W   = (const float*)d_in[2];
    const float* a   = (const float*)d_in[3];
    float* out = (float*)d_out;

    float*  s1     = (float*)d_ws;                 // 8192 f32
    float*  s2     = s1 + 8192;                    // 8192 f32 (pre-scaled log2e)
    ushort* whT_hi = (ushort*)(s2 + 8192);         // [64][8192] bf16
    ushort* whT_lo = whT_hi + 64 * 8192;           // [64][8192] bf16

    hipLaunchKernelGGL(k1_wh, dim3(512), dim3(256), 0, stream,
                       h, W, a, s1, s2, whT_hi, whT_lo);
    hipLaunchKernelGGL(k2_attn, dim3(256), dim3(512), 0, stream,
                       adj, s1, s2, whT_hi, whT_lo, out);
}